// Round 3
// baseline (651.189 us; speedup 1.0000x reference)
//
#include <hip/hip_runtime.h>
#include <math.h>

#define BSZ   4
#define SEQL  2048
#define DIN   40
#define DM    128
#define DI    256
#define DS    16
#define NL    4
#define NHEAD 4
#define DHEAD 32
#define KLM   100
#define NC    128       // chunks per sequence
#define TC    16        // SEQL / NC
#define PROWS 16        // rows per pre block
#define EROWS 16

__device__ __forceinline__ float sigmoidf_(float x){ return 1.0f/(1.0f + expf(-x)); }
__device__ __forceinline__ float siluf_(float x){ return x/(1.0f + expf(-x)); }
__device__ __forceinline__ float softplusf_(float x){ return fmaxf(x,0.0f) + log1pf(expf(-fabsf(x))); }

__device__ __forceinline__ float block_sum256(float v, float* red){
  #pragma unroll
  for (int o=32;o>0;o>>=1) v += __shfl_down(v,o,64);
  __syncthreads();
  if ((threadIdx.x & 63)==0) red[threadIdx.x>>6] = v;
  __syncthreads();
  return red[0]+red[1]+red[2]+red[3];
}
__device__ __forceinline__ void load16(const float* p, float* r){
  const float4* q = (const float4*)p;
  float4 a=q[0], b=q[1], c=q[2], d=q[3];
  r[0]=a.x;r[1]=a.y;r[2]=a.z;r[3]=a.w; r[4]=b.x;r[5]=b.y;r[6]=b.z;r[7]=b.w;
  r[8]=c.x;r[9]=c.y;r[10]=c.z;r[11]=c.w; r[12]=d.x;r[13]=d.y;r[14]=d.z;r[15]=d.w;
}
__device__ __forceinline__ void store16(float* p, const float* r){
  float4* q = (float4*)p;
  q[0]=make_float4(r[0],r[1],r[2],r[3]);  q[1]=make_float4(r[4],r[5],r[6],r[7]);
  q[2]=make_float4(r[8],r[9],r[10],r[11]);q[3]=make_float4(r[12],r[13],r[14],r[15]);
}

// ---------------- embed: 16 rows/block, weights amortized ----------------
__global__ __launch_bounds__(256) void embed_kernel(
    const float* __restrict__ x, const float* __restrict__ hw,
    const float* __restrict__ eW, const float* __restrict__ eb,
    const float* __restrict__ sW, const float* __restrict__ sb,
    float* __restrict__ hb, float* __restrict__ sk)
{
  __shared__ float xr[EROWS][DIN];
  const int t = threadIdx.x;
  const size_t R0 = (size_t)blockIdx.x * EROWS;
  for (int e=t; e<EROWS*DIN; e+=256) ((float*)xr)[e] = x[R0*DIN + e];
  __syncthreads();
  const int c = t & (DM-1), g = t >> 7;
  float ae[8], as[8];
  #pragma unroll
  for (int j=0;j<8;j++){ ae[j]=0.0f; as[j]=0.0f; }
  for (int k=0;k<DIN;k++){
    const float we  = eW[(size_t)k*DM + c];
    const float ws_ = sW[(size_t)k*DM + c];
    #pragma unroll
    for (int j=0;j<8;j++){
      const float xv = xr[g*8+j][k];
      ae[j] = fmaf(xv, we, ae[j]);
      as[j] = fmaf(xv, ws_, as[j]);
    }
  }
  const float ebv = eb[c], sbv = sb[c];
  #pragma unroll
  for (int j=0;j<8;j++){
    const size_t R = R0 + g*8 + j;
    const float w = hw[R];
    hb[R*DM + c] = (ae[j]+ebv)*w;
    sk[R*DM + c] = (as[j]+sbv)*w;
  }
}

// ---------------- per-layer "pre": LN -> in_proj -> silu -> x_proj -> B/C/dt/lam ----------------
// 512 threads, 16 rows/block, 512 blocks
__global__ __launch_bounds__(512) void pre_kernel(
    const float* __restrict__ hb,
    const float* __restrict__ Wi, const float* __restrict__ Wx,
    const float* __restrict__ Wdt, const float* __restrict__ bdt,
    const float* __restrict__ Bb, const float* __restrict__ Cb,
    const float* __restrict__ Bnw, const float* __restrict__ Cnw,
    const float* __restrict__ lnw, const float* __restrict__ lnb,
    float* __restrict__ xpb, float* __restrict__ zsb, float* __restrict__ dtb,
    float* __restrict__ Bmb, float* __restrict__ Cmb,
    float* __restrict__ lamb, float* __restrict__ mdtb)
{
  __shared__ float xin[PROWS][DM+4];     // 8.4 KB
  __shared__ float xps[PROWS][DI+4];     // 16.6 KB
  __shared__ float spl[PROWS][40];       // 2.5 KB
  __shared__ float pr[PROWS][4];

  const int t = threadIdx.x;
  const size_t R0 = (size_t)blockIdx.x * PROWS;

  { // LayerNorm: 32 threads per row
    const int r = t >> 5, j = t & 31;
    const float4 v = ((const float4*)(hb + (R0 + r)*DM))[j];
    float s = v.x+v.y+v.z+v.w;
    #pragma unroll
    for (int o=16;o>0;o>>=1) s += __shfl_xor(s,o,32);
    const float m = s*(1.0f/DM);
    const float dx=v.x-m, dy=v.y-m, dz=v.z-m, dw=v.w-m;
    float ss = dx*dx+dy*dy+dz*dz+dw*dw;
    #pragma unroll
    for (int o=16;o>0;o>>=1) ss += __shfl_xor(ss,o,32);
    const float inv = 1.0f/sqrtf(ss*(1.0f/DM) + 1e-5f);
    const int c = j*4;
    xin[r][c+0] = dx*inv*lnw[c+0] + lnb[c+0];
    xin[r][c+1] = dy*inv*lnw[c+1] + lnb[c+1];
    xin[r][c+2] = dz*inv*lnw[c+2] + lnb[c+2];
    xin[r][c+3] = dw*inv*lnw[c+3] + lnb[c+3];
  }
  __syncthreads();

  { // xz = xin @ Wi; thread t owns col t of [0,512); double-buffered weights
    float acc[PROWS];
    #pragma unroll
    for (int r=0;r<PROWS;r++) acc[r]=0.0f;
    float n0 = Wi[(size_t)0*(2*DI) + t];
    float n1 = Wi[(size_t)1*(2*DI) + t];
    float n2 = Wi[(size_t)2*(2*DI) + t];
    float n3 = Wi[(size_t)3*(2*DI) + t];
    for (int k=0;k<DM;k+=4){
      const float w0=n0, w1=n1, w2=n2, w3=n3;
      if (k+4 < DM){
        n0 = Wi[(size_t)(k+4)*(2*DI) + t];
        n1 = Wi[(size_t)(k+5)*(2*DI) + t];
        n2 = Wi[(size_t)(k+6)*(2*DI) + t];
        n3 = Wi[(size_t)(k+7)*(2*DI) + t];
      }
      #pragma unroll
      for (int r=0;r<PROWS;r++){
        const float4 xv = *(const float4*)&xin[r][k];
        float a = acc[r];
        a = fmaf(xv.x,w0,a); a = fmaf(xv.y,w1,a);
        a = fmaf(xv.z,w2,a); a = fmaf(xv.w,w3,a);
        acc[r] = a;
      }
    }
    if (t < DI){
      #pragma unroll
      for (int r=0;r<PROWS;r++){
        const float s = siluf_(acc[r]);
        xps[r][t] = s;
        xpb[(R0+r)*DI + t] = s;
      }
    } else {
      const int c = t - DI;
      #pragma unroll
      for (int r=0;r<PROWS;r++)
        zsb[(R0+r)*DI + c] = siluf_(acc[r]);
    }
  }
  __syncthreads();

  // sp = xp @ Wx.  t<256: (r = t>>4, o-pair o2 = t&15) covers o=0..31 (B,C)
  // t in [256,288): o=32 (dt_in), r=t-256 (r<16); t in [288,304): o=33 (lam_in)
  if (t < 256){
    const int r = t >> 4, o2 = t & 15;
    float ax=0.0f, ay=0.0f;
    for (int k=0;k<DI;k+=4){
      const float4 xv = *(const float4*)&xps[r][k];
      const float2 wv0 = *(const float2*)&Wx[(size_t)(k+0)*34 + 2*o2];
      const float2 wv1 = *(const float2*)&Wx[(size_t)(k+1)*34 + 2*o2];
      const float2 wv2 = *(const float2*)&Wx[(size_t)(k+2)*34 + 2*o2];
      const float2 wv3 = *(const float2*)&Wx[(size_t)(k+3)*34 + 2*o2];
      ax = fmaf(xv.x,wv0.x,ax); ay = fmaf(xv.x,wv0.y,ay);
      ax = fmaf(xv.y,wv1.x,ax); ay = fmaf(xv.y,wv1.y,ay);
      ax = fmaf(xv.z,wv2.x,ax); ay = fmaf(xv.z,wv2.y,ay);
      ax = fmaf(xv.w,wv3.x,ax); ay = fmaf(xv.w,wv3.y,ay);
    }
    spl[r][2*o2] = ax; spl[r][2*o2+1] = ay;
  } else if (t < 288+16){
    const int o = (t < 288) ? 32 : 33;
    const int r = (t < 288) ? (t-256) : (t-288);
    if (r < 16){
      float a = 0.0f;
      for (int k=0;k<DI;k+=4){
        const float4 xv = *(const float4*)&xps[r][k];
        a = fmaf(xv.x, Wx[(size_t)(k+0)*34 + o], a);
        a = fmaf(xv.y, Wx[(size_t)(k+1)*34 + o], a);
        a = fmaf(xv.z, Wx[(size_t)(k+2)*34 + o], a);
        a = fmaf(xv.w, Wx[(size_t)(k+3)*34 + o], a);
      }
      spl[r][o] = a;
    }
  }
  __syncthreads();

  { // B/C rms-norm: 512 tasks = 16 rows x 2 halves x 16 states
    const int half = t >> 8;          // 0: B, 1: C
    const int r2 = (t >> 4) & 15, s2 = t & 15;
    const float* bias = half ? Cb : Bb;
    const float* wn   = half ? Cnw : Bnw;
    const float v = spl[r2][half*DS + s2] + bias[s2];
    float ss = v*v;
    #pragma unroll
    for (int o=8;o>0;o>>=1) ss += __shfl_xor(ss,o,16);
    const float inv = 1.0f/sqrtf(ss*(1.0f/DS) + 1.1920929e-07f);
    (half ? Cmb : Bmb)[(R0+r2)*DS + s2] = v*inv*wn[s2];
  }

  { // dt: half = t>>8 handles rows half*8..half*8+7 at d = t&255
    const int half = t >> 8;
    const int d = t & 255;
    const int lane = t & 63;
    const int dgroup = (t >> 6) & 3;
    const float wdt = Wdt[d], bdtv = bdt[d];
    #pragma unroll
    for (int rr=0;rr<8;rr++){
      const int r = half*8 + rr;
      const float dval = softplusf_(fmaf(spl[r][32], wdt, bdtv));
      dtb[(R0+r)*DI + d] = dval;
      float s = dval;
      #pragma unroll
      for (int o=32;o>0;o>>=1) s += __shfl_xor(s,o,64);
      if (lane==0) pr[r][dgroup] = s;
    }
    if (t < PROWS) lamb[R0+t] = sigmoidf_(spl[t][33]);
  }
  __syncthreads();
  if (t < PROWS)
    mdtb[R0+t] = (pr[t][0]+pr[t][1]+pr[t][2]+pr[t][3])*(1.0f/DI);
}

// ---------------- fused cumsum (f64) + rope rotation; 256 thr, no spills ----------------
__global__ __launch_bounds__(256) void cumrot_kernel(
    const float* __restrict__ mdt, const float* __restrict__ rf,
    float* __restrict__ Bmb, float* __restrict__ Cmb)
{
  __shared__ double csum[SEQL];   // 16 KB
  __shared__ double wsum[4];
  __shared__ double fqs[8];
  const int b = blockIdx.x, t = threadIdx.x;
  const int lane = t & 63, w = t >> 6;
  if (t < 8){
    const double xfr = (double)rf[t];
    fqs[t] = fmax(xfr, 0.0) + log1p(exp(-fabs(xfr)));
  }
  const float* p = mdt + (size_t)b*SEQL + (size_t)t*8;
  double v[8]; double s = 0.0;
  #pragma unroll
  for (int q=0;q<8;q++){ v[q] = (double)p[q]; s += v[q]; }
  double sc = s;
  #pragma unroll
  for (int o=1;o<64;o<<=1){
    const double nb = __shfl_up(sc, o, 64);
    if (lane >= o) sc += nb;
  }
  if (lane==63) wsum[w] = sc;
  __syncthreads();
  double woff = 0.0;
  for (int j=0;j<w;j++) woff += wsum[j];
  double run = woff + sc - s;   // exclusive prefix for this thread's span
  #pragma unroll
  for (int q=0;q<8;q++){ run += v[q]; csum[t*8+q] = run; }
  __syncthreads();

  const double TWO_PI = 6.283185307179586;
  const double INV2PI = 0.15915494309189535;
  for (int j=0;j<8;j++){
    const int rloc = j*256 + t;
    const size_t row = (size_t)b*SEQL + rloc;
    const double ab = csum[rloc];
    float ca[8], sa[8];
    #pragma unroll
    for (int f=0; f<8; f++){
      const double ang = ab * fqs[f];
      const double red = ang - floor(ang*INV2PI)*TWO_PI;
      __sincosf((float)red, &sa[f], &ca[f]);
    }
    float B[16], C[16];
    load16(Bmb + row*DS, B); load16(Cmb + row*DS, C);
    #pragma unroll
    for (int f=0; f<8; f++){
      const float be=B[2*f], bo=B[2*f+1];
      B[2*f]   = be*ca[f] - bo*sa[f];
      B[2*f+1] = be*sa[f] + bo*ca[f];
      const float ce=C[2*f], co=C[2*f+1];
      C[2*f]   = ce*ca[f] - co*sa[f];
      C[2*f+1] = ce*sa[f] + co*ca[f];
    }
    store16(Bmb + row*DS, B); store16(Cmb + row*DS, C);
  }
}

// ---------------- scan phase 1: per-chunk local scan (h from 0) + decay product ----------------
__global__ __launch_bounds__(256) void scan1_kernel(
    const float* __restrict__ xp, const float* __restrict__ dtb,
    const float* __restrict__ Bmb, const float* __restrict__ lamb,
    const float* __restrict__ Alog, float* __restrict__ hend, float* __restrict__ Pp)
{
  __shared__ float Bst[TC+1][DS];
  __shared__ float lst[TC];
  const int t = threadIdx.x;
  const int d = t;
  const int c = blockIdx.x & (NC-1);
  const int b = blockIdx.x >> 7;
  const size_t bL = (size_t)b*SEQL;
  const int t0 = c*TC;
  const int id = blockIdx.x*256 + t;

  for (int e=t; e<(TC+1)*DS; e+=256){
    const int j = e >> 4, s = e & 15;
    const int trow = t0 - 1 + j;
    Bst[j][s] = (trow >= 0) ? Bmb[(bL + trow)*DS + s] : 0.0f;
  }
  if (t < TC) lst[t] = lamb[bL + t0 + t];
  __syncthreads();

  float A[DS];
  #pragma unroll
  for (int s=0;s<DS;s++) A[s] = fminf(-expf(Alog[d*DS+s]), -1e-4f);
  float h[DS], P[DS], Bprev[DS];
  #pragma unroll
  for (int s=0;s<DS;s++){ h[s]=0.0f; P[s]=1.0f; }
  float xpm1;
  int tstart;
  if (t0 > 0){
    #pragma unroll
    for (int s=0;s<DS;s++) Bprev[s] = Bst[0][s];
    xpm1 = xp[(bL + t0 - 1)*DI + d];
    tstart = t0;
  } else {
    const size_t rowE = bL*DI + d;
    const float dtv = dtb[rowE];
    const float xpv = xp[rowE];
    #pragma unroll
    for (int s=0;s<DS;s++){
      const float a = __expf(A[s]*dtv);
      h[s] = dtv*(Bst[1][s]*xpv);
      P[s] *= a;
      Bprev[s] = Bst[1][s];
    }
    xpm1 = xpv;
    tstart = 1;
  }
  for (int tt=tstart; tt<t0+TC; ++tt){
    const size_t rowE = (bL + tt)*DI + d;
    const float dtv = dtb[rowE];
    const float xpv = xp[rowE];
    const float lamv = lst[tt - t0];
    const int j = tt - t0 + 1;
    const float dl = dtv*lamv;
    const float dml = dtv - dl;
    #pragma unroll
    for (int s=0;s<DS;s++){
      const float a = __expf(A[s]*dtv);
      const float Bc = Bst[j][s];
      const float u = fmaf(dml*a, Bprev[s]*xpm1, dl*(Bc*xpv));
      h[s] = fmaf(a, h[s], u);
      P[s] *= a;
      Bprev[s] = Bc;
    }
    xpm1 = xpv;
  }
  store16(hend + (size_t)id*DS, h);
  store16(Pp   + (size_t)id*DS, P);
}

// ---------------- scan phase 2: sequential chunk combine; hend becomes Hin ----------------
__global__ __launch_bounds__(256) void scan2_kernel(float* __restrict__ hend, const float* __restrict__ Pp){
  const int id = blockIdx.x*256 + threadIdx.x;   // BSZ*DI*DS
  const int s = id & 15, d = (id >> 4) & (DI-1), b = id >> 12;
  float H = 0.0f;
  #pragma unroll 4
  for (int c=0;c<NC;c++){
    const size_t ix = (((size_t)(b*NC + c))*DI + d)*DS + s;
    const float he = hend[ix], p = Pp[ix];
    hend[ix] = H;          // chunk-initial state
    H = fmaf(p, H, he);
  }
}

// ---------------- scan phase 3 + out_proj + residual (fused) ----------------
__global__ __launch_bounds__(256) void scan3post_kernel(
    const float* __restrict__ xp, const float* __restrict__ dtb,
    const float* __restrict__ Bmb, const float* __restrict__ Cmb,
    const float* __restrict__ lamb, const float* __restrict__ zsb,
    const float* __restrict__ Alog, const float* __restrict__ Dv,
    const float* __restrict__ Hin, const float* __restrict__ Wo,
    float* __restrict__ hb)
{
  __shared__ float Bst[TC+1][DS];
  __shared__ float Cst[TC][DS];
  __shared__ float lst[TC];
  __shared__ float ys[TC][DI+4];
  const int t = threadIdx.x;
  const int d = t;
  const int c = blockIdx.x & (NC-1);
  const int b = blockIdx.x >> 7;
  const size_t bL = (size_t)b*SEQL;
  const int t0 = c*TC;
  const int id = blockIdx.x*256 + t;

  for (int e=t; e<(TC+1)*DS; e+=256){
    const int j = e >> 4, s = e & 15;
    const int trow = t0 - 1 + j;
    Bst[j][s] = (trow >= 0) ? Bmb[(bL + trow)*DS + s] : 0.0f;
    if (j < TC) Cst[j][s] = Cmb[(bL + t0 + j)*DS + s];
  }
  if (t < TC) lst[t] = lamb[bL + t0 + t];
  __syncthreads();

  float A[DS];
  #pragma unroll
  for (int s=0;s<DS;s++) A[s] = fminf(-expf(Alog[d*DS+s]), -1e-4f);
  const float dvp = Dv[d];
  float h[DS], Bprev[DS];
  load16(Hin + (size_t)id*DS, h);
  float xpm1;
  int tstart;
  if (t0 > 0){
    #pragma unroll
    for (int s=0;s<DS;s++) Bprev[s] = Bst[0][s];
    xpm1 = xp[(bL + t0 - 1)*DI + d];
    tstart = t0;
  } else {
    const size_t rowE = bL*DI + d;
    const float dtv = dtb[rowE];
    const float xpv = xp[rowE];
    float y = 0.0f;
    #pragma unroll
    for (int s=0;s<DS;s++){
      h[s] = dtv*(Bst[1][s]*xpv);   // h starts at 0
      y = fmaf(h[s], Cst[0][s], y);
      Bprev[s] = Bst[1][s];
    }
    ys[0][d] = (y + xpv*dvp)*zsb[rowE];
    xpm1 = xpv;
    tstart = 1;
  }
  for (int tt=tstart; tt<t0+TC; ++tt){
    const size_t rowE = (bL + tt)*DI + d;
    const float dtv = dtb[rowE];
    const float xpv = xp[rowE];
    const float lamv = lst[tt - t0];
    const int j = tt - t0;
    const float dl = dtv*lamv;
    const float dml = dtv - dl;
    float y = 0.0f;
    #pragma unroll
    for (int s=0;s<DS;s++){
      const float a = __expf(A[s]*dtv);
      const float Bc = Bst[j+1][s];
      const float u = fmaf(dml*a, Bprev[s]*xpm1, dl*(Bc*xpv));
      h[s] = fmaf(a, h[s], u);
      y = fmaf(h[s], Cst[j][s], y);
      Bprev[s] = Bc;
    }
    ys[j][d] = (y + xpv*dvp)*zsb[rowE];
    xpm1 = xpv;
  }
  __syncthreads();

  // out_proj (16 rows x 128 cols, K=256) + residual into hb
  {
    const int r  = t >> 4;         // 0..15
    const int cg = t & 15;
    const int c0 = cg*8;
    float acc[8];
    #pragma unroll
    for (int j=0;j<8;j++) acc[j]=0.0f;
    for (int k=0;k<DI;k+=4){
      const float4 yv = *(const float4*)&ys[r][k];
      const float yy[4] = {yv.x, yv.y, yv.z, yv.w};
      #pragma unroll
      for (int j=0;j<4;j++){
        const float4 wa = *(const float4*)&Wo[(size_t)(k+j)*DM + c0];
        const float4 wb = *(const float4*)&Wo[(size_t)(k+j)*DM + c0 + 4];
        acc[0]=fmaf(yy[j],wa.x,acc[0]); acc[1]=fmaf(yy[j],wa.y,acc[1]);
        acc[2]=fmaf(yy[j],wa.z,acc[2]); acc[3]=fmaf(yy[j],wa.w,acc[3]);
        acc[4]=fmaf(yy[j],wb.x,acc[4]); acc[5]=fmaf(yy[j],wb.y,acc[5]);
        acc[6]=fmaf(yy[j],wb.z,acc[6]); acc[7]=fmaf(yy[j],wb.w,acc[7]);
      }
    }
    const size_t row = bL + t0 + r;
    float4 h0 = *(const float4*)&hb[row*DM + c0];
    float4 h1 = *(const float4*)&hb[row*DM + c0 + 4];
    h0.x+=acc[0]; h0.y+=acc[1]; h0.z+=acc[2]; h0.w+=acc[3];
    h1.x+=acc[4]; h1.y+=acc[5]; h1.z+=acc[6]; h1.w+=acc[7];
    *(float4*)&hb[row*DM + c0]     = h0;
    *(float4*)&hb[row*DM + c0 + 4] = h1;
  }
}

// ---------------- final LN + landmark attention (one block per batch) ----------------
__global__ __launch_bounds__(256) void attn_kernel(
    const float* __restrict__ hb, const float* __restrict__ sk,
    const float* __restrict__ hw,
    const float* __restrict__ fnw, const float* __restrict__ fnb,
    const float* __restrict__ WQ, const float* __restrict__ bQ,
    const float* __restrict__ WK, const float* __restrict__ bK,
    const float* __restrict__ WV, const float* __restrict__ bV,
    const float* __restrict__ WO, const float* __restrict__ bO,
    float* __restrict__ outp)
{
  __shared__ float kv[KLM][DM+4];
  __shared__ float mo[DM];
  __shared__ float Qs[DM];
  __shared__ float qk[NHEAD][DM];
  __shared__ float bterm[NHEAD];
  __shared__ float sc[NHEAD][KLM];
  __shared__ float pbar[NHEAD][DM];
  __shared__ float attno[DM];
  __shared__ int idxl[KLM];
  __shared__ int redcnt[2][4];
  __shared__ int eqc[8][4], gtc[8][4];
  __shared__ float red_f[4];

  const int b = blockIdx.x;
  const int t = threadIdx.x;
  const int lane = t & 63, w = t >> 6;

  const float* hwp = hw + (size_t)b*SEQL;
  unsigned vb[8];
  #pragma unroll
  for (int q=0;q<8;q++) vb[q] = __float_as_uint(hwp[q*256 + t]);

  unsigned kth = 0u;
  for (int bit=31; bit>=0; --bit){
    const unsigned cand = kth | (1u << bit);
    int c0 = 0;
    #pragma unroll
    for (int q=0;q<8;q++) c0 += __popcll(__ballot(vb[q] >= cand));
    const int par = bit & 1;
    if (lane == 0) redcnt[par][w] = c0;
    __syncthreads();
    const int tot = redcnt[par][0]+redcnt[par][1]+redcnt[par][2]+redcnt[par][3];
    if (tot >= KLM) kth = cand;
  }

  unsigned long long beq[8], bgt[8];
  #pragma unroll
  for (int q=0;q<8;q++){
    beq[q] = __ballot(vb[q] == kth);
    bgt[q] = __ballot(vb[q] >  kth);
  }
  if (lane == 0){
    #pragma unroll
    for (int q=0;q<8;q++){ eqc[q][w] = __popcll(beq[q]); gtc[q][w] = __popcll(bgt[q]); }
  }
  __syncthreads();
  {
    int gtTot = 0;
    #pragma unroll
    for (int q=0;q<8;q++) gtTot += gtc[q][0]+gtc[q][1]+gtc[q][2]+gtc[q][3];
    const int need_eq = KLM - gtTot;
    const unsigned long long lmask = (lane==0) ? 0ull : ((~0ull) >> (64-lane));
    int eqPfx = 0, gtPfx = 0;
    #pragma unroll
    for (int q=0;q<8;q++){
      int eqWP = 0, gtWP = 0;
      for (int w2=0; w2<w; ++w2){ eqWP += eqc[q][w2]; gtWP += gtc[q][w2]; }
      const int eqBefore = eqPfx + eqWP + __popcll(beq[q] & lmask);
      const int gtBefore = gtPfx + gtWP + __popcll(bgt[q] & lmask);
      if (vb[q] > kth){
        const int pos = gtBefore + min(eqBefore, need_eq);
        if (pos < KLM) idxl[pos] = q*256 + t;
      } else if (vb[q] == kth && eqBefore < need_eq){
        const int pos = gtBefore + eqBefore;
        if (pos < KLM) idxl[pos] = q*256 + t;
      }
      eqPfx += eqc[q][0]+eqc[q][1]+eqc[q][2]+eqc[q][3];
      gtPfx += gtc[q][0]+gtc[q][1]+gtc[q][2]+gtc[q][3];
    }
  }
  __syncthreads();

  {
    const float* hr = hb + ((size_t)b*SEQL + (SEQL-1))*DM;
    const float hv = (t < DM) ? hr[t] : 0.0f;
    const float ssum = block_sum256(hv, red_f);
    const float mean = ssum*(1.0f/DM);
    const float dv = (t < DM) ? (hv - mean) : 0.0f;
    const float vsum = block_sum256(dv*dv, red_f);
    const float inv = 1.0f/sqrtf(vsum*(1.0f/DM) + 1e-5f);
    if (t < DM) mo[t] = dv*inv*fnw[t] + fnb[t];
  }
  __syncthreads();

  for (int e=t; e<KLM*DM; e+=256){
    const int j = e >> 7, cc = e & (DM-1);
    kv[j][cc] = sk[((size_t)b*SEQL + idxl[j])*DM + cc];
  }
  __syncthreads();

  if (t < DM){
    float a = bQ[t];
    #pragma unroll 4
    for (int k=0;k<DM;k++) a = fmaf(mo[k], WQ[(size_t)k*DM + t], a);
    Qs[t] = a;
  }
  __syncthreads();
  for (int e=t; e<NHEAD*DM; e+=256){
    const int hh = e >> 7, m = e & (DM-1);
    const int c0 = hh*DHEAD;
    float a = 0.0f;
    #pragma unroll
    for (int cc=0; cc<DHEAD; cc++) a = fmaf(WK[(size_t)m*DM + c0 + cc], Qs[c0+cc], a);
    qk[hh][m] = a;
  }
  if (t < NHEAD){
    float a = 0.0f;
    for (int cc=0; cc<DHEAD; cc++) a += bK[t*DHEAD+cc]*Qs[t*DHEAD+cc];
    bterm[t] = a;
  }
  __syncthreads();
  for (int e=t; e<NHEAD*KLM; e+=256){
    const int hh = e/KLM, j = e - hh*KLM;
    float a = bterm[hh];
    for (int m=0;m<DM;m+=4){
      const float4 kvv = *(const float4*)&kv[j][m];
      const float4 qv  = *(const float4*)&qk[hh][m];
      a = fmaf(kvv.x,qv.x,a); a = fmaf(kvv.y,qv.y,a);
      a = fmaf(kvv.z,qv.z,a); a = fmaf(kvv.w,qv.w,a);
    }
    sc[hh][j] = a*0.17677669529663687f;
  }
  __syncthreads();
  {
    const int hh = w;
    const float v0 = (lane < KLM) ? sc[hh][lane] : -3.0e38f;
    const float v1 = (lane+64 < KLM) ? sc[hh][lane+64] : -3.0e38f;
    float mx = fmaxf(v0, v1);
    #pragma unroll
    for (int o2=32;o2>0;o2>>=1) mx = fmaxf(mx, __shfl_xor(mx,o2,64));
    const float e0 = (lane < KLM) ? expf(v0-mx) : 0.0f;
    const float e1 = (lane+64 < KLM) ? expf(v1-mx) : 0.0f;
    float sm = e0+e1;
    #pragma unroll
    for (int o2=32;o2>0;o2>>=1) sm += __shfl_xor(sm,o2,64);
    const float inv2 = 1.0f/sm;
    if (lane < KLM) sc[hh][lane] = e0*inv2;
    if (lane+64 < KLM) sc[hh][lane+64] = e1*inv2;
  }
  __syncthreads();
  for (int e=t; e<NHEAD*DM; e+=256){
    const int hh = e >> 7, m = e & (DM-1);
    float a = 0.0f;
    #pragma unroll 4
    for (int j=0;j<KLM;j++) a = fmaf(sc[hh][j], kv[j][m], a);
    pbar[hh][m] = a;
  }
  __syncthreads();
  if (t < DM){
    const int hh = t >> 5;
    float a = bV[t];
    for (int m=0;m<DM;m+=4){
      const float4 pv = *(const float4*)&pbar[hh][m];
      a = fmaf(pv.x, WV[(size_t)(m+0)*DM + t], a);
      a = fmaf(pv.y, WV[(size_t)(m+1)*DM + t], a);
      a = fmaf(pv.z, WV[(size_t)(m+2)*DM + t], a);
      a = fmaf(pv.w, WV[(size_t)(m+3)*DM + t], a);
    }
    attno[t] = a;
  }
  __syncthreads();
  if (t < DM){
    float a = bO[t];
    #pragma unroll 4
    for (int c2=0;c2<DM;c2++) a = fmaf(attno[c2], WO[(size_t)c2*DM + t], a);
    outp[(size_t)b*DM + t] = a;
  }
}

extern "C" void kernel_launch(void* const* d_in, const int* in_sizes, int n_in,
                              void* d_out, int out_size, void* d_ws, size_t ws_size,
                              hipStream_t stream)
{
  (void)in_sizes; (void)n_in; (void)out_size; (void)ws_size;
  const float* x    = (const float*)d_in[0];
  const float* hw   = (const float*)d_in[1];
  const float* embW = (const float*)d_in[2];
  const float* embB = (const float*)d_in[3];
  const float* skW  = (const float*)d_in[4];
  const float* skB  = (const float*)d_in[5];
  const float* inW  = (const float*)d_in[6];
  const float* xpW  = (const float*)d_in[7];
  const float* dtW  = (const float*)d_in[8];
  const float* dtB  = (const float*)d_in[9];
  const float* Alog = (const float*)d_in[10];
  const float* Bb   = (const float*)d_in[11];
  const float* Cb   = (const float*)d_in[12];
  const float* Bnw  = (const float*)d_in[13];
  const float* Cnw  = (const float*)d_in[14];
  const float* rf   = (const float*)d_in[15];
  const float* Dpar = (const float*)d_in[16];
  const float* outW = (const float*)d_in[17];
  const float* lnW  = (const float*)d_in[18];
  const float* lnB  = (const float*)d_in[19];
  const float* fnW  = (const float*)d_in[20];
  const float* fnB  = (const float*)d_in[21];
  const float* WQ = (const float*)d_in[22]; const float* bQ = (const float*)d_in[23];
  const float* WK = (const float*)d_in[24]; const float* bK = (const float*)d_in[25];
  const float* WV = (const float*)d_in[26]; const float* bV = (const float*)d_in[27];
  const float* WO = (const float*)d_in[28]; const float* bO = (const float*)d_in[29];

  float* ws = (float*)d_ws;
  size_t off = 0;
  float* hb   = ws + off; off += (size_t)BSZ*SEQL*DM;
  float* sk   = ws + off; off += (size_t)BSZ*SEQL*DM;
  float* xpb  = ws + off; off += (size_t)BSZ*SEQL*DI;
  float* zsb  = ws + off; off += (size_t)BSZ*SEQL*DI;
  float* dtb  = ws + off; off += (size_t)BSZ*SEQL*DI;
  float* Bmb  = ws + off; off += (size_t)BSZ*SEQL*DS;
  float* Cmb  = ws + off; off += (size_t)BSZ*SEQL*DS;
  float* lamb = ws + off; off += (size_t)BSZ*SEQL;
  float* mdtb = ws + off; off += (size_t)BSZ*SEQL;
  float* hend = ws + off; off += (size_t)BSZ*NC*DI*DS;
  float* Ppb  = ws + off; off += (size_t)BSZ*NC*DI*DS;

  embed_kernel<<<BSZ*SEQL/EROWS, 256, 0, stream>>>(x, hw, embW, embB, skW, skB, hb, sk);

  for (int i=0;i<NL;i++){
    pre_kernel<<<BSZ*SEQL/PROWS, 512, 0, stream>>>(hb,
        inW + (size_t)i*DM*2*DI, xpW + (size_t)i*DI*34,
        dtW + (size_t)i*DI, dtB + (size_t)i*DI,
        Bb + i*DS, Cb + i*DS, Bnw + i*DS, Cnw + i*DS,
        lnW + i*DM, lnB + i*DM,
        xpb, zsb, dtb, Bmb, Cmb, lamb, mdtb);
    cumrot_kernel<<<BSZ, 256, 0, stream>>>(mdtb, rf + i*8, Bmb, Cmb);
    scan1_kernel<<<BSZ*NC, 256, 0, stream>>>(xpb, dtb, Bmb, lamb,
        Alog + (size_t)i*DI*DS, hend, Ppb);
    scan2_kernel<<<BSZ*DI*DS/256, 256, 0, stream>>>(hend, Ppb);
    scan3post_kernel<<<BSZ*NC, 256, 0, stream>>>(xpb, dtb, Bmb, Cmb, lamb, zsb,
        Alog + (size_t)i*DI*DS, Dpar + (size_t)i*DI, hend,
        outW + (size_t)i*DI*DM, hb);
  }

  attn_kernel<<<BSZ, 256, 0, stream>>>(hb, sk, hw, fnW, fnB,
      WQ, bQ, WK, bK, WV, bV, WO, bO, (float*)d_out);
}

// Round 4
// 605.367 us; speedup vs baseline: 1.0757x; 1.0757x over previous
//
#include <hip/hip_runtime.h>
#include <math.h>

#define BSZ   4
#define SEQL  2048
#define DIN   40
#define DM    128
#define DI    256
#define DS    16
#define NL    4
#define NHEAD 4
#define DHEAD 32
#define KLM   100
#define NC    128       // chunks per sequence
#define TC    16        // SEQL / NC
#define PROWS 16        // rows per pre block
#define EROWS 16

__device__ __forceinline__ float sigmoidf_(float x){ return 1.0f/(1.0f + expf(-x)); }
__device__ __forceinline__ float siluf_(float x){ return x/(1.0f + expf(-x)); }
__device__ __forceinline__ float softplusf_(float x){ return fmaxf(x,0.0f) + log1pf(expf(-fabsf(x))); }

__device__ __forceinline__ float block_sum256(float v, float* red){
  #pragma unroll
  for (int o=32;o>0;o>>=1) v += __shfl_down(v,o,64);
  __syncthreads();
  if ((threadIdx.x & 63)==0) red[threadIdx.x>>6] = v;
  __syncthreads();
  return red[0]+red[1]+red[2]+red[3];
}
__device__ __forceinline__ void load16(const float* p, float* r){
  const float4* q = (const float4*)p;
  float4 a=q[0], b=q[1], c=q[2], d=q[3];
  r[0]=a.x;r[1]=a.y;r[2]=a.z;r[3]=a.w; r[4]=b.x;r[5]=b.y;r[6]=b.z;r[7]=b.w;
  r[8]=c.x;r[9]=c.y;r[10]=c.z;r[11]=c.w; r[12]=d.x;r[13]=d.y;r[14]=d.z;r[15]=d.w;
}
__device__ __forceinline__ void store16(float* p, const float* r){
  float4* q = (float4*)p;
  q[0]=make_float4(r[0],r[1],r[2],r[3]);  q[1]=make_float4(r[4],r[5],r[6],r[7]);
  q[2]=make_float4(r[8],r[9],r[10],r[11]);q[3]=make_float4(r[12],r[13],r[14],r[15]);
}

// ---------------- embed: 16 rows/block, weights amortized ----------------
__global__ __launch_bounds__(256) void embed_kernel(
    const float* __restrict__ x, const float* __restrict__ hw,
    const float* __restrict__ eW, const float* __restrict__ eb,
    const float* __restrict__ sW, const float* __restrict__ sb,
    float* __restrict__ hb, float* __restrict__ sk)
{
  __shared__ float xr[EROWS][DIN];
  const int t = threadIdx.x;
  const size_t R0 = (size_t)blockIdx.x * EROWS;
  for (int e=t; e<EROWS*DIN; e+=256) ((float*)xr)[e] = x[R0*DIN + e];
  __syncthreads();
  const int c = t & (DM-1), g = t >> 7;
  float ae[8], as[8];
  #pragma unroll
  for (int j=0;j<8;j++){ ae[j]=0.0f; as[j]=0.0f; }
  for (int k=0;k<DIN;k++){
    const float we  = eW[(size_t)k*DM + c];
    const float ws_ = sW[(size_t)k*DM + c];
    #pragma unroll
    for (int j=0;j<8;j++){
      const float xv = xr[g*8+j][k];
      ae[j] = fmaf(xv, we, ae[j]);
      as[j] = fmaf(xv, ws_, as[j]);
    }
  }
  const float ebv = eb[c], sbv = sb[c];
  #pragma unroll
  for (int j=0;j<8;j++){
    const size_t R = R0 + g*8 + j;
    const float w = hw[R];
    hb[R*DM + c] = (ae[j]+ebv)*w;
    sk[R*DM + c] = (as[j]+sbv)*w;
  }
}

// ---------------- per-layer "pre": LN -> in_proj -> silu -> x_proj -> B/C/dt/lam ----------------
// 256 threads, 16 rows/block, 512 blocks. in_proj: thread=(colquad, rowhalf), C=4 cols via float4.
__global__ __launch_bounds__(256) void pre_kernel(
    const float* __restrict__ hb,
    const float* __restrict__ Wi, const float* __restrict__ Wx,
    const float* __restrict__ Wdt, const float* __restrict__ bdt,
    const float* __restrict__ Bb, const float* __restrict__ Cb,
    const float* __restrict__ Bnw, const float* __restrict__ Cnw,
    const float* __restrict__ lnw, const float* __restrict__ lnb,
    float* __restrict__ xpb, float* __restrict__ zsb, float* __restrict__ dtb,
    float* __restrict__ Bmb, float* __restrict__ Cmb,
    float* __restrict__ lamb, float* __restrict__ mdtb)
{
  __shared__ float xin[PROWS][DM+4];     // 8.4 KB
  __shared__ float xps[PROWS][DI+4];     // 16.6 KB
  __shared__ float spl[PROWS][40];       // 2.5 KB
  __shared__ float pr[PROWS][4];

  const int t = threadIdx.x;
  const size_t R0 = (size_t)blockIdx.x * PROWS;

  { // LayerNorm: 16 threads per row, 8 floats each
    const int r = t >> 4, j = t & 15;
    const float* hr = hb + (R0 + r)*DM + j*8;
    const float4 v0 = *(const float4*)hr;
    const float4 v1 = *(const float4*)(hr+4);
    float s = v0.x+v0.y+v0.z+v0.w + v1.x+v1.y+v1.z+v1.w;
    #pragma unroll
    for (int o=8;o>0;o>>=1) s += __shfl_xor(s,o,16);
    const float m = s*(1.0f/DM);
    const float d0=v0.x-m,d1=v0.y-m,d2=v0.z-m,d3=v0.w-m;
    const float d4=v1.x-m,d5=v1.y-m,d6=v1.z-m,d7=v1.w-m;
    float ss = d0*d0+d1*d1+d2*d2+d3*d3+d4*d4+d5*d5+d6*d6+d7*d7;
    #pragma unroll
    for (int o=8;o>0;o>>=1) ss += __shfl_xor(ss,o,16);
    const float inv = 1.0f/sqrtf(ss*(1.0f/DM) + 1e-5f);
    const int c = j*8;
    xin[r][c+0]=d0*inv*lnw[c+0]+lnb[c+0]; xin[r][c+1]=d1*inv*lnw[c+1]+lnb[c+1];
    xin[r][c+2]=d2*inv*lnw[c+2]+lnb[c+2]; xin[r][c+3]=d3*inv*lnw[c+3]+lnb[c+3];
    xin[r][c+4]=d4*inv*lnw[c+4]+lnb[c+4]; xin[r][c+5]=d5*inv*lnw[c+5]+lnb[c+5];
    xin[r][c+6]=d6*inv*lnw[c+6]+lnb[c+6]; xin[r][c+7]=d7*inv*lnw[c+7]+lnb[c+7];
  }
  __syncthreads();

  { // in_proj: cq = col quad (4 cols), rh = row half (8 rows)
    const int cq = t & 127;
    const int rh = t >> 7;
    const int r0 = rh*8;
    float4 acc[8];
    #pragma unroll
    for (int r=0;r<8;r++) acc[r] = make_float4(0.f,0.f,0.f,0.f);
    const float* Wc = Wi + 4*cq;
    for (int k=0;k<DM;k+=4){
      const float4 w0 = *(const float4*)&Wc[(size_t)(k+0)*(2*DI)];
      const float4 w1 = *(const float4*)&Wc[(size_t)(k+1)*(2*DI)];
      const float4 w2 = *(const float4*)&Wc[(size_t)(k+2)*(2*DI)];
      const float4 w3 = *(const float4*)&Wc[(size_t)(k+3)*(2*DI)];
      #pragma unroll
      for (int r=0;r<8;r++){
        const float4 xv = *(const float4*)&xin[r0+r][k];
        float4 a = acc[r];
        a.x=fmaf(xv.x,w0.x,a.x); a.y=fmaf(xv.x,w0.y,a.y); a.z=fmaf(xv.x,w0.z,a.z); a.w=fmaf(xv.x,w0.w,a.w);
        a.x=fmaf(xv.y,w1.x,a.x); a.y=fmaf(xv.y,w1.y,a.y); a.z=fmaf(xv.y,w1.z,a.z); a.w=fmaf(xv.y,w1.w,a.w);
        a.x=fmaf(xv.z,w2.x,a.x); a.y=fmaf(xv.z,w2.y,a.y); a.z=fmaf(xv.z,w2.z,a.z); a.w=fmaf(xv.z,w2.w,a.w);
        a.x=fmaf(xv.w,w3.x,a.x); a.y=fmaf(xv.w,w3.y,a.y); a.z=fmaf(xv.w,w3.z,a.z); a.w=fmaf(xv.w,w3.w,a.w);
        acc[r] = a;
      }
    }
    const int col = 4*cq;
    if (col < DI){
      #pragma unroll
      for (int r=0;r<8;r++){
        float4 s;
        s.x=siluf_(acc[r].x); s.y=siluf_(acc[r].y); s.z=siluf_(acc[r].z); s.w=siluf_(acc[r].w);
        *(float4*)&xps[r0+r][col] = s;
        *(float4*)&xpb[(R0+r0+r)*DI + col] = s;
      }
    } else {
      const int zc = col - DI;
      #pragma unroll
      for (int r=0;r<8;r++){
        float4 s;
        s.x=siluf_(acc[r].x); s.y=siluf_(acc[r].y); s.z=siluf_(acc[r].z); s.w=siluf_(acc[r].w);
        *(float4*)&zsb[(R0+r0+r)*DI + zc] = s;
      }
    }
  }
  __syncthreads();

  // sp = xp @ Wx. 272 tasks = 16 rows x 17 col-pairs (pair op=16 -> cols 32,33)
  for (int e=t; e<272; e+=256){
    const int r = e & 15, op = e >> 4;
    float ax=0.0f, ay=0.0f;
    for (int k=0;k<DI;k+=4){
      const float4 xv = *(const float4*)&xps[r][k];
      const float2 w0 = *(const float2*)&Wx[(size_t)(k+0)*34 + 2*op];
      const float2 w1 = *(const float2*)&Wx[(size_t)(k+1)*34 + 2*op];
      const float2 w2 = *(const float2*)&Wx[(size_t)(k+2)*34 + 2*op];
      const float2 w3 = *(const float2*)&Wx[(size_t)(k+3)*34 + 2*op];
      ax = fmaf(xv.x,w0.x,ax); ay = fmaf(xv.x,w0.y,ay);
      ax = fmaf(xv.y,w1.x,ax); ay = fmaf(xv.y,w1.y,ay);
      ax = fmaf(xv.z,w2.x,ax); ay = fmaf(xv.z,w2.y,ay);
      ax = fmaf(xv.w,w3.x,ax); ay = fmaf(xv.w,w3.y,ay);
    }
    spl[r][2*op] = ax; spl[r][2*op+1] = ay;
  }
  __syncthreads();

  { // B/C rms-norm: thread (r, s) does both B and C
    const int r = t >> 4, s = t & 15;
    const float vB = spl[r][s] + Bb[s];
    float ssB = vB*vB;
    #pragma unroll
    for (int o=8;o>0;o>>=1) ssB += __shfl_xor(ssB,o,16);
    Bmb[(R0+r)*DS + s] = vB * (1.0f/sqrtf(ssB*(1.0f/DS) + 1.1920929e-07f)) * Bnw[s];
    const float vC = spl[r][DS+s] + Cb[s];
    float ssC = vC*vC;
    #pragma unroll
    for (int o=8;o>0;o>>=1) ssC += __shfl_xor(ssC,o,16);
    Cmb[(R0+r)*DS + s] = vC * (1.0f/sqrtf(ssC*(1.0f/DS) + 1.1920929e-07f)) * Cnw[s];
  }

  { // dt: d = t covers DI; loop rows; wave-partial means
    const int lane = t & 63, w = t >> 6;
    const float wdt = Wdt[t], bdtv = bdt[t];
    #pragma unroll 4
    for (int r=0;r<PROWS;r++){
      const float dval = softplusf_(fmaf(spl[r][32], wdt, bdtv));
      dtb[(R0+r)*DI + t] = dval;
      float s = dval;
      #pragma unroll
      for (int o=32;o>0;o>>=1) s += __shfl_xor(s,o,64);
      if (lane==0) pr[r][w] = s;
    }
    if (t < PROWS) lamb[R0+t] = sigmoidf_(spl[t][33]);
  }
  __syncthreads();
  if (t < PROWS)
    mdtb[R0+t] = (pr[t][0]+pr[t][1]+pr[t][2]+pr[t][3])*(1.0f/DI);
}

// ---------------- cumsum (f64) + cos/sin table; rotation applied in scan kernels ----------------
__global__ __launch_bounds__(256) void cumsum_cs_kernel(
    const float* __restrict__ mdt, const float* __restrict__ rf,
    float2* __restrict__ cst)
{
  __shared__ double csum[SEQL];   // 16 KB
  __shared__ double wsum[4];
  __shared__ double fqs[8];
  const int b = blockIdx.x, t = threadIdx.x;
  const int lane = t & 63, w = t >> 6;
  if (t < 8){
    const double xfr = (double)rf[t];
    fqs[t] = fmax(xfr, 0.0) + log1p(exp(-fabs(xfr)));
  }
  const float* p = mdt + (size_t)b*SEQL + (size_t)t*8;
  double v[8]; double s = 0.0;
  #pragma unroll
  for (int q=0;q<8;q++){ v[q] = (double)p[q]; s += v[q]; }
  double sc = s;
  #pragma unroll
  for (int o=1;o<64;o<<=1){
    const double nb = __shfl_up(sc, o, 64);
    if (lane >= o) sc += nb;
  }
  if (lane==63) wsum[w] = sc;
  __syncthreads();
  double woff = 0.0;
  for (int j=0;j<w;j++) woff += wsum[j];
  double run = woff + sc - s;
  #pragma unroll
  for (int q=0;q<8;q++){ run += v[q]; csum[t*8+q] = run; }
  __syncthreads();

  const double TWO_PI = 6.283185307179586;
  const double INV2PI = 0.15915494309189535;
  for (int j=0;j<8;j++){
    const int rloc = j*256 + t;
    const double ab = csum[rloc];
    float2 o8[8];
    #pragma unroll
    for (int f=0; f<8; f++){
      const double ang = ab * fqs[f];
      const double red = ang - floor(ang*INV2PI)*TWO_PI;
      float sa, ca;
      __sincosf((float)red, &sa, &ca);
      o8[f] = make_float2(ca, sa);
    }
    float4* dst = (float4*)&cst[((size_t)b*SEQL + rloc)*8];
    dst[0] = make_float4(o8[0].x,o8[0].y,o8[1].x,o8[1].y);
    dst[1] = make_float4(o8[2].x,o8[2].y,o8[3].x,o8[3].y);
    dst[2] = make_float4(o8[4].x,o8[4].y,o8[5].x,o8[5].y);
    dst[3] = make_float4(o8[6].x,o8[6].y,o8[7].x,o8[7].y);
  }
}

// ---------------- scan phase 1: per-chunk local scan (rotation fused) ----------------
__global__ __launch_bounds__(256) void scan1_kernel(
    const float* __restrict__ xp, const float* __restrict__ dtb,
    const float* __restrict__ Bmb, const float* __restrict__ lamb,
    const float2* __restrict__ cst,
    const float* __restrict__ Alog, float* __restrict__ hend, float* __restrict__ Pp)
{
  __shared__ float Bst[TC+1][DS];
  __shared__ float lst[TC];
  const int t = threadIdx.x;
  const int d = t;
  const int c = blockIdx.x & (NC-1);
  const int b = blockIdx.x >> 7;
  const size_t bL = (size_t)b*SEQL;
  const int t0 = c*TC;
  const int id = blockIdx.x*256 + t;

  for (int e=t; e<(TC+1)*DS; e+=256){
    const int j = e >> 4, s = e & 15;
    const int trow = t0 - 1 + j;
    Bst[j][s] = (trow >= 0) ? Bmb[(bL + trow)*DS + s] : 0.0f;
  }
  if (t < TC) lst[t] = lamb[bL + t0 + t];
  __syncthreads();
  // rotate staged B rows
  if (t < 136){
    const int j = t >> 3, f = t & 7;
    const int trow = t0 - 1 + j;
    if (trow >= 0){
      const float2 cs = cst[((size_t)(bL + trow))*8 + f];
      const float e0 = Bst[j][2*f], o0 = Bst[j][2*f+1];
      Bst[j][2*f]   = e0*cs.x - o0*cs.y;
      Bst[j][2*f+1] = e0*cs.y + o0*cs.x;
    }
  }
  __syncthreads();

  float A[DS];
  #pragma unroll
  for (int s=0;s<DS;s++) A[s] = fminf(-expf(Alog[d*DS+s]), -1e-4f);
  float h[DS], P[DS], Bprev[DS];
  #pragma unroll
  for (int s=0;s<DS;s++){ h[s]=0.0f; P[s]=1.0f; }
  float xpm1;
  int tstart;
  if (t0 > 0){
    #pragma unroll
    for (int s=0;s<DS;s++) Bprev[s] = Bst[0][s];
    xpm1 = xp[(bL + t0 - 1)*DI + d];
    tstart = t0;
  } else {
    const size_t rowE = bL*DI + d;
    const float dtv = dtb[rowE];
    const float xpv = xp[rowE];
    #pragma unroll
    for (int s=0;s<DS;s++){
      const float a = __expf(A[s]*dtv);
      h[s] = dtv*(Bst[1][s]*xpv);
      P[s] *= a;
      Bprev[s] = Bst[1][s];
    }
    xpm1 = xpv;
    tstart = 1;
  }
  for (int tt=tstart; tt<t0+TC; ++tt){
    const size_t rowE = (bL + tt)*DI + d;
    const float dtv = dtb[rowE];
    const float xpv = xp[rowE];
    const float lamv = lst[tt - t0];
    const int j = tt - t0 + 1;
    const float dl = dtv*lamv;
    const float dml = dtv - dl;
    #pragma unroll
    for (int s=0;s<DS;s++){
      const float a = __expf(A[s]*dtv);
      const float Bc = Bst[j][s];
      const float u = fmaf(dml*a, Bprev[s]*xpm1, dl*(Bc*xpv));
      h[s] = fmaf(a, h[s], u);
      P[s] *= a;
      Bprev[s] = Bc;
    }
    xpm1 = xpv;
  }
  store16(hend + (size_t)id*DS, h);
  store16(Pp   + (size_t)id*DS, P);
}

// ---------------- scan phase 2: sequential chunk combine; hend becomes Hin ----------------
__global__ __launch_bounds__(256) void scan2_kernel(float* __restrict__ hend, const float* __restrict__ Pp){
  const int id = blockIdx.x*256 + threadIdx.x;   // BSZ*DI*DS
  const int s = id & 15, d = (id >> 4) & (DI-1), b = id >> 12;
  float H = 0.0f;
  #pragma unroll 4
  for (int c=0;c<NC;c++){
    const size_t ix = (((size_t)(b*NC + c))*DI + d)*DS + s;
    const float he = hend[ix], p = Pp[ix];
    hend[ix] = H;          // chunk-initial state
    H = fmaf(p, H, he);
  }
}

// ---------------- scan phase 3 + out_proj + residual (rotation fused) ----------------
__global__ __launch_bounds__(256) void scan3post_kernel(
    const float* __restrict__ xp, const float* __restrict__ dtb,
    const float* __restrict__ Bmb, const float* __restrict__ Cmb,
    const float* __restrict__ lamb, const float* __restrict__ zsb,
    const float2* __restrict__ cst,
    const float* __restrict__ Alog, const float* __restrict__ Dv,
    const float* __restrict__ Hin, const float* __restrict__ Wo,
    float* __restrict__ hb)
{
  __shared__ float Bst[TC+1][DS];
  __shared__ float Cst[TC][DS];
  __shared__ float lst[TC];
  __shared__ float ys[TC][DI+4];
  const int t = threadIdx.x;
  const int d = t;
  const int c = blockIdx.x & (NC-1);
  const int b = blockIdx.x >> 7;
  const size_t bL = (size_t)b*SEQL;
  const int t0 = c*TC;
  const int id = blockIdx.x*256 + t;

  for (int e=t; e<(TC+1)*DS; e+=256){
    const int j = e >> 4, s = e & 15;
    const int trow = t0 - 1 + j;
    Bst[j][s] = (trow >= 0) ? Bmb[(bL + trow)*DS + s] : 0.0f;
    if (j < TC) Cst[j][s] = Cmb[(bL + t0 + j)*DS + s];
  }
  if (t < TC) lst[t] = lamb[bL + t0 + t];
  __syncthreads();
  // rotate staged B (136 tasks) and C (128 tasks)
  for (int e=t; e<264; e+=256){
    if (e < 136){
      const int j = e >> 3, f = e & 7;
      const int trow = t0 - 1 + j;
      if (trow >= 0){
        const float2 cs = cst[((size_t)(bL + trow))*8 + f];
        const float e0 = Bst[j][2*f], o0 = Bst[j][2*f+1];
        Bst[j][2*f]   = e0*cs.x - o0*cs.y;
        Bst[j][2*f+1] = e0*cs.y + o0*cs.x;
      }
    } else {
      const int e2 = e - 136;
      const int j = e2 >> 3, f = e2 & 7;
      const float2 cs = cst[((size_t)(bL + t0 + j))*8 + f];
      const float e0 = Cst[j][2*f], o0 = Cst[j][2*f+1];
      Cst[j][2*f]   = e0*cs.x - o0*cs.y;
      Cst[j][2*f+1] = e0*cs.y + o0*cs.x;
    }
  }
  __syncthreads();

  float A[DS];
  #pragma unroll
  for (int s=0;s<DS;s++) A[s] = fminf(-expf(Alog[d*DS+s]), -1e-4f);
  const float dvp = Dv[d];
  float h[DS], Bprev[DS];
  load16(Hin + (size_t)id*DS, h);
  float xpm1;
  int tstart;
  if (t0 > 0){
    #pragma unroll
    for (int s=0;s<DS;s++) Bprev[s] = Bst[0][s];
    xpm1 = xp[(bL + t0 - 1)*DI + d];
    tstart = t0;
  } else {
    const size_t rowE = bL*DI + d;
    const float dtv = dtb[rowE];
    const float xpv = xp[rowE];
    float y = 0.0f;
    #pragma unroll
    for (int s=0;s<DS;s++){
      h[s] = dtv*(Bst[1][s]*xpv);   // h starts at 0
      y = fmaf(h[s], Cst[0][s], y);
      Bprev[s] = Bst[1][s];
    }
    ys[0][d] = (y + xpv*dvp)*zsb[rowE];
    xpm1 = xpv;
    tstart = 1;
  }
  for (int tt=tstart; tt<t0+TC; ++tt){
    const size_t rowE = (bL + tt)*DI + d;
    const float dtv = dtb[rowE];
    const float xpv = xp[rowE];
    const float lamv = lst[tt - t0];
    const int j = tt - t0;
    const float dl = dtv*lamv;
    const float dml = dtv - dl;
    float y = 0.0f;
    #pragma unroll
    for (int s=0;s<DS;s++){
      const float a = __expf(A[s]*dtv);
      const float Bc = Bst[j+1][s];
      const float u = fmaf(dml*a, Bprev[s]*xpm1, dl*(Bc*xpv));
      h[s] = fmaf(a, h[s], u);
      y = fmaf(h[s], Cst[j][s], y);
      Bprev[s] = Bc;
    }
    ys[j][d] = (y + xpv*dvp)*zsb[rowE];
    xpm1 = xpv;
  }
  __syncthreads();

  // out_proj (16 rows x 128 cols, K=256) + residual into hb
  {
    const int r  = t >> 4;         // 0..15
    const int cg = t & 15;
    const int c0 = cg*8;
    float acc[8];
    #pragma unroll
    for (int j=0;j<8;j++) acc[j]=0.0f;
    for (int k=0;k<DI;k+=4){
      const float4 yv = *(const float4*)&ys[r][k];
      const float yy[4] = {yv.x, yv.y, yv.z, yv.w};
      #pragma unroll
      for (int j=0;j<4;j++){
        const float4 wa = *(const float4*)&Wo[(size_t)(k+j)*DM + c0];
        const float4 wb = *(const float4*)&Wo[(size_t)(k+j)*DM + c0 + 4];
        acc[0]=fmaf(yy[j],wa.x,acc[0]); acc[1]=fmaf(yy[j],wa.y,acc[1]);
        acc[2]=fmaf(yy[j],wa.z,acc[2]); acc[3]=fmaf(yy[j],wa.w,acc[3]);
        acc[4]=fmaf(yy[j],wb.x,acc[4]); acc[5]=fmaf(yy[j],wb.y,acc[5]);
        acc[6]=fmaf(yy[j],wb.z,acc[6]); acc[7]=fmaf(yy[j],wb.w,acc[7]);
      }
    }
    const size_t row = bL + t0 + r;
    float4 h0 = *(const float4*)&hb[row*DM + c0];
    float4 h1 = *(const float4*)&hb[row*DM + c0 + 4];
    h0.x+=acc[0]; h0.y+=acc[1]; h0.z+=acc[2]; h0.w+=acc[3];
    h1.x+=acc[4]; h1.y+=acc[5]; h1.z+=acc[6]; h1.w+=acc[7];
    *(float4*)&hb[row*DM + c0]     = h0;
    *(float4*)&hb[row*DM + c0 + 4] = h1;
  }
}

// ---------------- final LN + landmark attention (one block per batch) ----------------
__global__ __launch_bounds__(256) void attn_kernel(
    const float* __restrict__ hb, const float* __restrict__ sk,
    const float* __restrict__ hw,
    const float* __restrict__ fnw, const float* __restrict__ fnb,
    const float* __restrict__ WQ, const float* __restrict__ bQ,
    const float* __restrict__ WK, const float* __restrict__ bK,
    const float* __restrict__ WV, const float* __restrict__ bV,
    const float* __restrict__ WO, const float* __restrict__ bO,
    float* __restrict__ outp)
{
  __shared__ float kv[KLM][DM+4];
  __shared__ float mo[DM];
  __shared__ float Qs[DM];
  __shared__ float qk[NHEAD][DM];
  __shared__ float bterm[NHEAD];
  __shared__ float sc[NHEAD][KLM];
  __shared__ float pbar[NHEAD][DM];
  __shared__ float attno[DM];
  __shared__ int idxl[KLM];
  __shared__ int redcnt[2][4];
  __shared__ int eqc[8][4], gtc[8][4];
  __shared__ float red_f[4];

  const int b = blockIdx.x;
  const int t = threadIdx.x;
  const int lane = t & 63, w = t >> 6;

  const float* hwp = hw + (size_t)b*SEQL;
  unsigned vb[8];
  #pragma unroll
  for (int q=0;q<8;q++) vb[q] = __float_as_uint(hwp[q*256 + t]);

  unsigned kth = 0u;
  for (int bit=31; bit>=0; --bit){
    const unsigned cand = kth | (1u << bit);
    int c0 = 0;
    #pragma unroll
    for (int q=0;q<8;q++) c0 += __popcll(__ballot(vb[q] >= cand));
    const int par = bit & 1;
    if (lane == 0) redcnt[par][w] = c0;
    __syncthreads();
    const int tot = redcnt[par][0]+redcnt[par][1]+redcnt[par][2]+redcnt[par][3];
    if (tot >= KLM) kth = cand;
  }

  unsigned long long beq[8], bgt[8];
  #pragma unroll
  for (int q=0;q<8;q++){
    beq[q] = __ballot(vb[q] == kth);
    bgt[q] = __ballot(vb[q] >  kth);
  }
  if (lane == 0){
    #pragma unroll
    for (int q=0;q<8;q++){ eqc[q][w] = __popcll(beq[q]); gtc[q][w] = __popcll(bgt[q]); }
  }
  __syncthreads();
  {
    int gtTot = 0;
    #pragma unroll
    for (int q=0;q<8;q++) gtTot += gtc[q][0]+gtc[q][1]+gtc[q][2]+gtc[q][3];
    const int need_eq = KLM - gtTot;
    const unsigned long long lmask = (lane==0) ? 0ull : ((~0ull) >> (64-lane));
    int eqPfx = 0, gtPfx = 0;
    #pragma unroll
    for (int q=0;q<8;q++){
      int eqWP = 0, gtWP = 0;
      for (int w2=0; w2<w; ++w2){ eqWP += eqc[q][w2]; gtWP += gtc[q][w2]; }
      const int eqBefore = eqPfx + eqWP + __popcll(beq[q] & lmask);
      const int gtBefore = gtPfx + gtWP + __popcll(bgt[q] & lmask);
      if (vb[q] > kth){
        const int pos = gtBefore + min(eqBefore, need_eq);
        if (pos < KLM) idxl[pos] = q*256 + t;
      } else if (vb[q] == kth && eqBefore < need_eq){
        const int pos = gtBefore + eqBefore;
        if (pos < KLM) idxl[pos] = q*256 + t;
      }
      eqPfx += eqc[q][0]+eqc[q][1]+eqc[q][2]+eqc[q][3];
      gtPfx += gtc[q][0]+gtc[q][1]+gtc[q][2]+gtc[q][3];
    }
  }
  __syncthreads();

  {
    const float* hr = hb + ((size_t)b*SEQL + (SEQL-1))*DM;
    const float hv = (t < DM) ? hr[t] : 0.0f;
    const float ssum = block_sum256(hv, red_f);
    const float mean = ssum*(1.0f/DM);
    const float dv = (t < DM) ? (hv - mean) : 0.0f;
    const float vsum = block_sum256(dv*dv, red_f);
    const float inv = 1.0f/sqrtf(vsum*(1.0f/DM) + 1e-5f);
    if (t < DM) mo[t] = dv*inv*fnw[t] + fnb[t];
  }
  __syncthreads();

  for (int e=t; e<KLM*DM; e+=256){
    const int j = e >> 7, cc = e & (DM-1);
    kv[j][cc] = sk[((size_t)b*SEQL + idxl[j])*DM + cc];
  }
  __syncthreads();

  if (t < DM){
    float a = bQ[t];
    #pragma unroll 4
    for (int k=0;k<DM;k++) a = fmaf(mo[k], WQ[(size_t)k*DM + t], a);
    Qs[t] = a;
  }
  __syncthreads();
  for (int e=t; e<NHEAD*DM; e+=256){
    const int hh = e >> 7, m = e & (DM-1);
    const int c0 = hh*DHEAD;
    float a = 0.0f;
    #pragma unroll
    for (int cc=0; cc<DHEAD; cc++) a = fmaf(WK[(size_t)m*DM + c0 + cc], Qs[c0+cc], a);
    qk[hh][m] = a;
  }
  if (t < NHEAD){
    float a = 0.0f;
    for (int cc=0; cc<DHEAD; cc++) a += bK[t*DHEAD+cc]*Qs[t*DHEAD+cc];
    bterm[t] = a;
  }
  __syncthreads();
  for (int e=t; e<NHEAD*KLM; e+=256){
    const int hh = e/KLM, j = e - hh*KLM;
    float a = bterm[hh];
    for (int m=0;m<DM;m+=4){
      const float4 kvv = *(const float4*)&kv[j][m];
      const float4 qv  = *(const float4*)&qk[hh][m];
      a = fmaf(kvv.x,qv.x,a); a = fmaf(kvv.y,qv.y,a);
      a = fmaf(kvv.z,qv.z,a); a = fmaf(kvv.w,qv.w,a);
    }
    sc[hh][j] = a*0.17677669529663687f;
  }
  __syncthreads();
  {
    const int hh = w;
    const float v0 = (lane < KLM) ? sc[hh][lane] : -3.0e38f;
    const float v1 = (lane+64 < KLM) ? sc[hh][lane+64] : -3.0e38f;
    float mx = fmaxf(v0, v1);
    #pragma unroll
    for (int o2=32;o2>0;o2>>=1) mx = fmaxf(mx, __shfl_xor(mx,o2,64));
    const float e0 = (lane < KLM) ? expf(v0-mx) : 0.0f;
    const float e1 = (lane+64 < KLM) ? expf(v1-mx) : 0.0f;
    float sm = e0+e1;
    #pragma unroll
    for (int o2=32;o2>0;o2>>=1) sm += __shfl_xor(sm,o2,64);
    const float inv2 = 1.0f/sm;
    if (lane < KLM) sc[hh][lane] = e0*inv2;
    if (lane+64 < KLM) sc[hh][lane+64] = e1*inv2;
  }
  __syncthreads();
  for (int e=t; e<NHEAD*DM; e+=256){
    const int hh = e >> 7, m = e & (DM-1);
    float a = 0.0f;
    #pragma unroll 4
    for (int j=0;j<KLM;j++) a = fmaf(sc[hh][j], kv[j][m], a);
    pbar[hh][m] = a;
  }
  __syncthreads();
  if (t < DM){
    const int hh = t >> 5;
    float a = bV[t];
    for (int m=0;m<DM;m+=4){
      const float4 pv = *(const float4*)&pbar[hh][m];
      a = fmaf(pv.x, WV[(size_t)(m+0)*DM + t], a);
      a = fmaf(pv.y, WV[(size_t)(m+1)*DM + t], a);
      a = fmaf(pv.z, WV[(size_t)(m+2)*DM + t], a);
      a = fmaf(pv.w, WV[(size_t)(m+3)*DM + t], a);
    }
    attno[t] = a;
  }
  __syncthreads();
  if (t < DM){
    float a = bO[t];
    #pragma unroll 4
    for (int c2=0;c2<DM;c2++) a = fmaf(attno[c2], WO[(size_t)c2*DM + t], a);
    outp[(size_t)b*DM + t] = a;
  }
}

extern "C" void kernel_launch(void* const* d_in, const int* in_sizes, int n_in,
                              void* d_out, int out_size, void* d_ws, size_t ws_size,
                              hipStream_t stream)
{
  (void)in_sizes; (void)n_in; (void)out_size; (void)ws_size;
  const float* x    = (const float*)d_in[0];
  const float* hw   = (const float*)d_in[1];
  const float* embW = (const float*)d_in[2];
  const float* embB = (const float*)d_in[3];
  const float* skW  = (const float*)d_in[4];
  const float* skB  = (const float*)d_in[5];
  const float* inW  = (const float*)d_in[6];
  const float* xpW  = (const float*)d_in[7];
  const float* dtW  = (const float*)d_in[8];
  const float* dtB  = (const float*)d_in[9];
  const float* Alog = (const float*)d_in[10];
  const float* Bb   = (const float*)d_in[11];
  const float* Cb   = (const float*)d_in[12];
  const float* Bnw  = (const float*)d_in[13];
  const float* Cnw  = (const float*)d_in[14];
  const float* rf   = (const float*)d_in[15];
  const float* Dpar = (const float*)d_in[16];
  const float* outW = (const float*)d_in[17];
  const float* lnW  = (const float*)d_in[18];
  const float* lnB  = (const float*)d_in[19];
  const float* fnW  = (const float*)d_in[20];
  const float* fnB  = (const float*)d_in[21];
  const float* WQ = (const float*)d_in[22]; const float* bQ = (const float*)d_in[23];
  const float* WK = (const float*)d_in[24]; const float* bK = (const float*)d_in[25];
  const float* WV = (const float*)d_in[26]; const float* bV = (const float*)d_in[27];
  const float* WO = (const float*)d_in[28]; const float* bO = (const float*)d_in[29];

  float* ws = (float*)d_ws;
  size_t off = 0;
  float* hb   = ws + off; off += (size_t)BSZ*SEQL*DM;
  float* sk   = ws + off; off += (size_t)BSZ*SEQL*DM;
  float* xpb  = ws + off; off += (size_t)BSZ*SEQL*DI;
  float* zsb  = ws + off; off += (size_t)BSZ*SEQL*DI;
  float* dtb  = ws + off; off += (size_t)BSZ*SEQL*DI;
  float* Bmb  = ws + off; off += (size_t)BSZ*SEQL*DS;
  float* Cmb  = ws + off; off += (size_t)BSZ*SEQL*DS;
  float* lamb = ws + off; off += (size_t)BSZ*SEQL;
  float* mdtb = ws + off; off += (size_t)BSZ*SEQL;
  float* hend = ws + off; off += (size_t)BSZ*NC*DI*DS;
  float* Ppb  = ws + off; off += (size_t)BSZ*NC*DI*DS;
  float2* cst = (float2*)(ws + off);                     // BSZ*SEQL*8 float2

  embed_kernel<<<BSZ*SEQL/EROWS, 256, 0, stream>>>(x, hw, embW, embB, skW, skB, hb, sk);

  for (int i=0;i<NL;i++){
    pre_kernel<<<BSZ*SEQL/PROWS, 256, 0, stream>>>(hb,
        inW + (size_t)i*DM*2*DI, xpW + (size_t)i*DI*34,
        dtW + (size_t)i*DI, dtB + (size_t)i*DI,
        Bb + i*DS, Cb + i*DS, Bnw + i*DS, Cnw + i*DS,
        lnW + i*DM, lnB + i*DM,
        xpb, zsb, dtb, Bmb, Cmb, lamb, mdtb);
    cumsum_cs_kernel<<<BSZ, 256, 0, stream>>>(mdtb, rf + i*8, cst);
    scan1_kernel<<<BSZ*NC, 256, 0, stream>>>(xpb, dtb, Bmb, lamb, cst,
        Alog + (size_t)i*DI*DS, hend, Ppb);
    scan2_kernel<<<BSZ*DI*DS/256, 256, 0, stream>>>(hend, Ppb);
    scan3post_kernel<<<BSZ*NC, 256, 0, stream>>>(xpb, dtb, Bmb, Cmb, lamb, zsb, cst,
        Alog + (size_t)i*DI*DS, Dpar + (size_t)i*DI, hend,
        outW + (size_t)i*DI*DM, hb);
  }

  attn_kernel<<<BSZ, 256, 0, stream>>>(hb, sk, hw, fnW, fnB,
      WQ, bQ, WK, bK, WV, bV, WO, bO, (float*)d_out);
}